// Round 1
// 261.321 us; speedup vs baseline: 1.0106x; 1.0106x over previous
//
#include <hip/hip_runtime.h>
#include <hip/hip_bf16.h>

// ---------- helpers ----------

typedef __attribute__((ext_vector_type(8))) short bf16x8;
typedef __attribute__((ext_vector_type(4))) float f32x4;

#define AS_G(p) ((__attribute__((address_space(1))) void*)(p))
#define AS_L(p) ((__attribute__((address_space(3))) void*)(p))

__device__ __forceinline__ unsigned short f2bf(float f) {
  unsigned int u = __float_as_uint(f);
  unsigned int lsb = (u >> 16) & 1u;
  u += 0x7fffu + lsb;
  return (unsigned short)(u >> 16);
}

// Pipeline primitives: counted vmcnt (loads stay in flight across barriers),
// raw s_barrier (NOT __syncthreads(), which would emit s_waitcnt vmcnt(0) and
// drain the global_load_lds queue every K-step -- the old kernel's ~640 TF
// ceiling). Empty "memory"-clobber asm pins plain LDS loads between barriers.
#define WAITV(n) asm volatile("s_waitcnt vmcnt(" #n ")" ::: "memory")
#define WAITL0   asm volatile("s_waitcnt lgkmcnt(0)" ::: "memory")
#define BARRIER() do { __builtin_amdgcn_s_barrier(); asm volatile("" ::: "memory"); } while (0)

// ---------- deep-pipelined NT GEMM: C = A * B^T ----------
// A[m,k] lda, B[n,k] ldb, bf16, K-contiguous. Tile 256x128, BK=64,
// 512 threads = 8 waves (4M x 2N), per-wave 64x64 = 4x4 MFMA 16x16x32.
// LDS: 3 buffers x (A 256x64 + B 128x64) bf16 = 3 x 48 KiB = 144 KiB.
// Depth-2 prefetch: at iter it, stage tile it+2, then s_waitcnt vmcnt(12)
// guarantees tile it's 6 loads (issued 2 iters ago) have landed while 12
// loads stay in flight across both barriers.
// Swizzle (proven 0-conflict): row = 8 chunks of 8 elems (16B); slot s of
// row r holds global k-chunk s ^ (r&7); staging pre-swizzles the GLOBAL
// source so the LDS destination stays linear (global_load_lds requirement).
//
// EPI=1: QK epilogue. P' = bf16(exp(acc*scale)) (unnormalized softmax
//        numerator; no max-subtract needed: |acc*scale| <= ~1.5 by
//        construction), plus fp32 atomic row-sum accumulation into rsum.
// EPI=2: QKV projection split epilogue: col seg 0 -> qb (+bq), seg 1 -> kb
//        (+bk), seg 2 -> vt TRANSPOSED (+bv) as ushort4.
// EPI=3: PV epilogue: out fp32 = acc / rsum[row].

#define STAGE(ktk, bb) do {                                                          \
    unsigned short* dA_ = lds + (bb) * 24576;                                        \
    unsigned short* dB_ = dA_ + 16384;                                               \
    _Pragma("unroll")                                                                \
    for (int u_ = 0; u_ < 4; u_++)                                                   \
      __builtin_amdgcn_global_load_lds(                                              \
          AS_G(A + (size_t)(rowBase + r0 + 64 * u_) * lda + (ktk) + goff),           \
          AS_L(dA_ + ((size_t)t + 512 * u_) * 8), 16, 0, 0);                         \
    _Pragma("unroll")                                                                \
    for (int u_ = 0; u_ < 2; u_++)                                                   \
      __builtin_amdgcn_global_load_lds(                                              \
          AS_G(B + (size_t)(colBase + r0 + 64 * u_) * ldb + (ktk) + goff),           \
          AS_L(dB_ + ((size_t)t + 512 * u_) * 8), 16, 0, 0);                         \
  } while (0)

template <int EPI>
__global__ __launch_bounds__(512, 2) void gemm_pipe(
    const unsigned short* __restrict__ A, const unsigned short* __restrict__ B,
    float* __restrict__ Cf, long long sA, long long sB, long long sC,
    int K, int lda, int ldb, int ldc,
    unsigned short* __restrict__ u0, unsigned short* __restrict__ u1,
    unsigned short* __restrict__ u2,
    const float* __restrict__ f0, const float* __restrict__ f1,
    const float* __restrict__ f2,
    float* __restrict__ rsum, float scale)
{
  __shared__ unsigned short lds[3 * 24576];  // 147456 B (gfx950 allows 160 KiB/WG)

  const int t = threadIdx.x;
  const int rowBase = blockIdx.y * 256;
  const int colBase = blockIdx.x * 128;
  A += (long long)blockIdx.z * sA;
  B += (long long)blockIdx.z * sB;

  const int l = t & 63;
  const int w = t >> 6;            // 0..7
  const int wrow = (w >> 1) * 64;  // 0,64,128,192
  const int wcol = (w & 1) * 64;   // 0,64
  const int q = l >> 4;
  const int r16 = l & 15;

  // staging: thread t stages A chunks t+512u (u=0..3), B chunks t+512u (u=0..1).
  // chunk c: row=c>>3, slot=c&7, global k-chunk = slot ^ (row&7).
  const int r0 = t >> 3;                        // 0..63
  const int goff = ((t & 7) ^ (r0 & 7)) << 3;   // (r0+64u)&7 == r0&7

  f32x4 acc[4][4] = {};

  const int NT = K >> 6;

  // prologue: tiles 0 and 1 in flight
  STAGE(0, 0);
  STAGE(64, 1);

  int cur = 0;
  for (int it = 0; it < NT; ++it) {
    const int kt = it << 6;
    if (it + 2 < NT) {
      int b2 = cur + 2; if (b2 >= 3) b2 -= 3;   // == (it+2)%3; read-safe: B2 of iter it-1
      STAGE(kt + 128, b2);
      WAITV(12);    // oldest 6 (tile it) landed; 12 stay in flight
    } else if (it + 1 < NT) {
      WAITV(6);
    } else {
      WAITV(0);
    }
    BARRIER();      // B1: buffer `cur` fully staged by ALL waves

    const unsigned short* bufA = lds + cur * 24576;
    const unsigned short* bufB = bufA + 16384;
    bf16x8 af[2][4], bfr[2][4];
#pragma unroll
    for (int ks = 0; ks < 2; ks++) {
      const int s = (((ks * 4 + q) ^ (r16 & 7)) << 3);
#pragma unroll
      for (int i = 0; i < 4; i++)
        af[ks][i] = *(const bf16x8*)(bufA + (wrow + i * 16 + r16) * 64 + s);
#pragma unroll
      for (int j = 0; j < 4; j++)
        bfr[ks][j] = *(const bf16x8*)(bufB + (wcol + j * 16 + r16) * 64 + s);
    }
    __builtin_amdgcn_s_setprio(1);
#pragma unroll
    for (int ks = 0; ks < 2; ks++)
#pragma unroll
      for (int i = 0; i < 4; i++)
#pragma unroll
        for (int j = 0; j < 4; j++)
          acc[i][j] = __builtin_amdgcn_mfma_f32_16x16x32_bf16(af[ks][i], bfr[ks][j], acc[i][j], 0, 0, 0);
    __builtin_amdgcn_s_setprio(0);
    WAITL0;         // this wave's reads of `cur` complete
    BARRIER();      // B2: all waves done reading `cur` -> restage-safe next iter
    cur++; if (cur >= 3) cur -= 3;
  }

  // epilogues: C layout row=(lane>>4)*4+r, col=lane&15 (m89/m91 verified)
  if (EPI == 1) {
    unsigned short* p16 = u0 + (long long)blockIdx.z * sC;
    float* rs = rsum + (long long)blockIdx.z * 2048;
#pragma unroll
    for (int i = 0; i < 4; i++) {
#pragma unroll
      for (int r = 0; r < 4; r++) {
        int row = rowBase + wrow + i * 16 + q * 4 + r;
        float rowpart = 0.f;
#pragma unroll
        for (int j = 0; j < 4; j++) {
          int col = colBase + wcol + j * 16 + r16;
          float e = __expf(acc[i][j][r] * scale);
          p16[(size_t)row * ldc + col] = f2bf(e);
          rowpart += e;
        }
        // reduce across the 16 lanes of the quad (same row)
#pragma unroll
        for (int m = 1; m < 16; m <<= 1) rowpart += __shfl_xor(rowpart, m);
        if (r16 == 0) atomicAdd(rs + row, rowpart);
      }
    }
  } else if (EPI == 2) {
    const int seg = colBase >> 10;  // block-uniform
    if (seg < 2) {
      unsigned short* dst = seg ? u1 : u0;
      const float* bias = seg ? f1 : f0;
      const int cb = colBase & 1023;
#pragma unroll
      for (int i = 0; i < 4; i++) {
#pragma unroll
        for (int r = 0; r < 4; r++) {
          int row = rowBase + wrow + i * 16 + q * 4 + r;
#pragma unroll
          for (int j = 0; j < 4; j++) {
            int col = cb + wcol + j * 16 + r16;
            dst[(size_t)row * 1024 + col] = f2bf(acc[i][j][r] + bias[col]);
          }
        }
      }
    } else {
      const int ob = colBase - 2048;
#pragma unroll
      for (int i = 0; i < 4; i++) {
        int posBase = rowBase + wrow + i * 16 + q * 4;
        int b = posBase >> 11;
        int pos = posBase & 2047;
#pragma unroll
        for (int j = 0; j < 4; j++) {
          int o = ob + wcol + j * 16 + r16;
          float bias = f2[o];
          ushort4 pk;
          pk.x = f2bf(acc[i][j][0] + bias);
          pk.y = f2bf(acc[i][j][1] + bias);
          pk.z = f2bf(acc[i][j][2] + bias);
          pk.w = f2bf(acc[i][j][3] + bias);
          *(ushort4*)(u2 + ((size_t)((b << 10) + o) * 2048 + pos)) = pk;
        }
      }
    }
  } else {  // EPI == 3
    float* C = Cf + (long long)blockIdx.z * sC;
    const float* rs = rsum + (long long)blockIdx.z * 2048;
#pragma unroll
    for (int i = 0; i < 4; i++) {
#pragma unroll
      for (int r = 0; r < 4; r++) {
        int row = rowBase + wrow + i * 16 + q * 4 + r;
        float inv = 1.0f / rs[row];
#pragma unroll
        for (int j = 0; j < 4; j++) {
          int col = colBase + wcol + j * 16 + r16;
          C[(size_t)row * ldc + col] = acc[i][j][r] * inv;
        }
      }
    }
  }
}

// ---------- fp32 -> bf16 cast (vectorized) + rsum zero-fill ----------

__global__ __launch_bounds__(256) void cast_f32_to_bf16(
    const float* __restrict__ in, unsigned short* __restrict__ out, int n4,
    float* __restrict__ rzero, int nz4)
{
  int i = blockIdx.x * 256 + threadIdx.x;
  if (i < nz4) ((float4*)rzero)[i] = make_float4(0.f, 0.f, 0.f, 0.f);
  if (i >= n4) return;
  float4 v = ((const float4*)in)[i];
  ushort4 o;
  o.x = f2bf(v.x); o.y = f2bf(v.y); o.z = f2bf(v.z); o.w = f2bf(v.w);
  ((ushort4*)out)[i] = o;
}

// ---------- W transpose: WT[z][h, d] = bf16(W_z[d, h]), 1024x1024, z=0..2 ----------

__global__ __launch_bounds__(256) void wtrans(
    const float* __restrict__ Wq, const float* __restrict__ Wk,
    const float* __restrict__ Wv, unsigned short* __restrict__ WT)
{
  __shared__ float tile[32][33];
  const float* in = blockIdx.z == 0 ? Wq : (blockIdx.z == 1 ? Wk : Wv);
  unsigned short* out = WT + (size_t)blockIdx.z * 1024 * 1024;
  const int bc = blockIdx.x * 32;  // h
  const int br = blockIdx.y * 32;  // d
  const int tx = threadIdx.x;
  const int ty = threadIdx.y;
#pragma unroll
  for (int i = 0; i < 4; i++)
    tile[ty + i * 8][tx] = in[(size_t)(br + ty + i * 8) * 1024 + bc + tx];
  __syncthreads();
#pragma unroll
  for (int i = 0; i < 4; i++)
    out[(size_t)(bc + ty + i * 8) * 1024 + br + tx] = f2bf(tile[tx][ty + i * 8]);
}

// ---------- driver ----------

extern "C" void kernel_launch(void* const* d_in, const int* in_sizes, int n_in,
                              void* d_out, int out_size, void* d_ws, size_t ws_size,
                              hipStream_t stream) {
  (void)in_sizes; (void)n_in; (void)out_size;

  const float* x  = (const float*)d_in[0];
  const float* Wq = (const float*)d_in[1];
  const float* bq = (const float*)d_in[2];
  const float* Wk = (const float*)d_in[3];
  const float* bk = (const float*)d_in[4];
  const float* Wv = (const float*)d_in[5];
  const float* bv = (const float*)d_in[6];
  float* out = (float*)d_out;

  const int Nb = 4, L = 2048, D = 1024, H = 1024, O = 1024;
  const int M = Nb * L;      // 8192
  const int NQKV = 3 * H;    // 3072

  char* ws = (char*)d_ws;
  size_t off = 0;
  unsigned short* xb = (unsigned short*)(ws + off); off += (size_t)M * D * 2;
  unsigned short* qb = (unsigned short*)(ws + off); off += (size_t)M * H * 2;
  unsigned short* kb = (unsigned short*)(ws + off); off += (size_t)M * H * 2;
  unsigned short* vt = (unsigned short*)(ws + off); off += (size_t)M * O * 2;
  unsigned short* WT = (unsigned short*)(ws + off); off += (size_t)NQKV * D * 2;
  unsigned short* P  = (unsigned short*)(ws + off); off += (size_t)Nb * L * L * 2;
  float* rsum = (float*)(ws + off); off += (size_t)Nb * L * 4;
  if (ws_size < off) return;

  dim3 blk256(256);
  dim3 blk512(512);

  // x -> bf16, and zero the row-sum accumulator (ws is poisoned every call)
  cast_f32_to_bf16<<<(M * D / 4 + 255) / 256, blk256, 0, stream>>>(
      x, xb, M * D / 4, rsum, Nb * L / 4);

  // WT = concat(Wq^T, Wk^T, Wv^T) as bf16 [3072, 1024] (one launch, z=3)
  wtrans<<<dim3(32, 32, 3), dim3(32, 8), 0, stream>>>(Wq, Wk, Wv, WT);

  // fused projections: q -> qb, k -> kb, v -> vt (transposed), + biases
  // grid 24x32 = 768 blocks = 3.0 full CU rounds
  gemm_pipe<2><<<dim3(NQKV / 128, M / 256, 1), blk512, 0, stream>>>(
      xb, WT, nullptr, 0, 0, 0, D, D, D, 0,
      qb, kb, vt, bq, bk, bv, nullptr, 0.f);

  // QK + exp + row-sum atomics: P'[b] = exp(q k^T * scale), rsum[b][l] = row sums
  // grid 16x8x4 = 512 blocks = 2.0 rounds
  gemm_pipe<1><<<dim3(L / 128, L / 256, Nb), blk512, 0, stream>>>(
      qb, kb, nullptr, (long long)L * H, (long long)L * H, (long long)L * L,
      H, H, H, L,
      P, nullptr, nullptr, nullptr, nullptr, nullptr,
      rsum, 0.022097086912079608f /* 1/sqrt(2048) */);

  // out[b] = (P'[b] @ vt[b]^T) / rsum
  // grid 8x8x4 = 256 blocks = 1.0 round
  gemm_pipe<3><<<dim3(O / 128, L / 256, Nb), blk512, 0, stream>>>(
      P, vt, out, (long long)L * L, (long long)O * L, (long long)L * O,
      L, L, L, O,
      nullptr, nullptr, nullptr, nullptr, nullptr, nullptr,
      rsum, 0.f);
}

// Round 2
// 259.421 us; speedup vs baseline: 1.0180x; 1.0073x over previous
//
#include <hip/hip_runtime.h>
#include <hip/hip_bf16.h>

// ---------- helpers ----------

typedef __attribute__((ext_vector_type(8))) short bf16x8;
typedef __attribute__((ext_vector_type(4))) float f32x4;

#define AS_G(p) ((__attribute__((address_space(1))) void*)(p))
#define AS_L(p) ((__attribute__((address_space(3))) void*)(p))

__device__ __forceinline__ unsigned short f2bf(float f) {
  unsigned int u = __float_as_uint(f);
  unsigned int lsb = (u >> 16) & 1u;
  u += 0x7fffu + lsb;
  return (unsigned short)(u >> 16);
}

#define WAITV0 asm volatile("s_waitcnt vmcnt(0)" ::: "memory")
#define BARRIER() do { __builtin_amdgcn_s_barrier(); asm volatile("" ::: "memory"); } while (0)

// ---------- 256x256 8-phase NT GEMM: C = A * B^T (m201-style schedule) ----------
// A[m,k] lda, B[n,k] ldb, bf16, K-contiguous. BM=BN=256, BK=64.
// 512 threads = 8 waves (2M x 4N); per-wave C-tile 128x64 (8x4 frags of
// 16x16), acc[8][4]. LDS = 2 buffers x (A 256x64 + B 256x64) bf16 = 128 KiB.
// Swizzle (measured 0 SQ_LDS_BANK_CONFLICT): LDS row = 8 chunks of 8 elems
// (16B); slot s of row r holds global k-chunk s ^ (r&7); staging pre-swizzles
// the GLOBAL source so the LDS destination stays linear (global_load_lds
// wave-linear requirement).
//
// Per K-tile: 4 phases = C-quadrants (ih,jh) of 16 MFMA each, order
// (0,0)(0,1)(1,1)(1,0) so A/B fragment registers are reused across phases
// (ds_reads per phase: 12/4/8/0). Staging of K-tile t+1 (4 half-tiles,
// 2 global_load_lds each) is issued in phases p0/p1 of tile t -> every load
// is 2.5-3.5 phases (~1000+ cyc) old at the single vmcnt(0) drain at end of
// p3, so the drain is near-free, and loads stay in flight across 6 barriers.
// Strict double-buffer: every stage targets the buffer whose readers passed
// a barrier in the previous K-tile -> no read/write race surface.
//
// EPI=1: QK epilogue. P' = bf16(exp(acc*scale)) (unnormalized softmax
//        numerator; |acc*scale| small by construction), + fp32 atomic
//        row-sum into rsum.
// EPI=2: QKV projection split epilogue: col seg 0 -> qb (+bq), seg 1 -> kb
//        (+bk), seg 2 -> vt TRANSPOSED (+bv) as ushort4.
// EPI=3: PV epilogue: out fp32 = acc / rsum[row].

#define STAGE_A(ktk, h, bofs) do { _Pragma("unroll")                               \
    for (int u_ = 0; u_ < 2; u_++)                                                 \
      __builtin_amdgcn_global_load_lds(                                            \
          AS_G(A + (size_t)(rowBase + (h) * 128 + u_ * 64 + r0) * lda + (ktk) + goff), \
          AS_L(lds + (bofs) + ((h) * 128 + u_ * 64) * 64 + t * 8), 16, 0, 0);      \
  } while (0)

#define STAGE_B(ktk, h, bofs) do { _Pragma("unroll")                               \
    for (int u_ = 0; u_ < 2; u_++)                                                 \
      __builtin_amdgcn_global_load_lds(                                            \
          AS_G(B + (size_t)(colBase + (h) * 128 + u_ * 64 + r0) * ldb + (ktk) + goff), \
          AS_L(lds + (bofs) + 16384 + ((h) * 128 + u_ * 64) * 64 + t * 8), 16, 0, 0); \
  } while (0)

#define LOAD_A(ih, bofs) do { _Pragma("unroll")                                    \
    for (int ks_ = 0; ks_ < 2; ks_++) { _Pragma("unroll")                          \
      for (int ii = 0; ii < 4; ii++) {                                             \
        int row_ = wrow + ((ih) * 4 + ii) * 16 + r16;                              \
        int slot_ = (ks_ * 4 + q) ^ (r16 & 7);                                     \
        af[ks_][ii] = *(const bf16x8*)(lds + (bofs) + row_ * 64 + slot_ * 8);      \
      } } } while (0)

#define LOAD_B(jh, bofs) do { _Pragma("unroll")                                    \
    for (int ks_ = 0; ks_ < 2; ks_++) { _Pragma("unroll")                          \
      for (int jj = 0; jj < 2; jj++) {                                             \
        int row_ = wcol + ((jh) * 2 + jj) * 16 + r16;                              \
        int slot_ = (ks_ * 4 + q) ^ (r16 & 7);                                     \
        bfr[ks_][(jh) * 2 + jj] =                                                  \
            *(const bf16x8*)(lds + (bofs) + 16384 + row_ * 64 + slot_ * 8);        \
      } } } while (0)

#define MM(ih, jh) do { __builtin_amdgcn_s_setprio(1); _Pragma("unroll")           \
    for (int ks_ = 0; ks_ < 2; ks_++) { _Pragma("unroll")                          \
      for (int ii = 0; ii < 4; ii++) { _Pragma("unroll")                           \
        for (int jj = 0; jj < 2; jj++)                                             \
          acc[(ih) * 4 + ii][(jh) * 2 + jj] =                                      \
              __builtin_amdgcn_mfma_f32_16x16x32_bf16(                             \
                  af[ks_][ii], bfr[ks_][(jh) * 2 + jj],                            \
                  acc[(ih) * 4 + ii][(jh) * 2 + jj], 0, 0, 0);                     \
      } }                                                                          \
    __builtin_amdgcn_s_setprio(0); } while (0)

// One K-tile = 4 phases. Stages for tile t+1 go out in p0/p1; single
// vmcnt(0) drain at end of p3 (loads are 2.5+ phases old there).
#define KTILE(ktk, bofs, obofs, doStage) do {                                      \
    /* p0 (ih0,jh0) */                                                             \
    LOAD_A(0, bofs); LOAD_B(0, bofs);                                              \
    if (doStage) { STAGE_B((ktk) + 64, 1, obofs); STAGE_A((ktk) + 64, 0, obofs); } \
    BARRIER(); MM(0, 0); BARRIER();                                                \
    /* p1 (ih0,jh1) */                                                             \
    LOAD_B(1, bofs);                                                               \
    if (doStage) { STAGE_A((ktk) + 64, 1, obofs); STAGE_B((ktk) + 64, 0, obofs); } \
    BARRIER(); MM(0, 1); BARRIER();                                                \
    /* p2 (ih1,jh1) */                                                             \
    LOAD_A(1, bofs);                                                               \
    BARRIER(); MM(1, 1); BARRIER();                                                \
    /* p3 (ih1,jh0): pure MFMA + drain + publish */                                \
    MM(1, 0); WAITV0; BARRIER(); } while (0)

template <int EPI>
__global__ __launch_bounds__(512, 2) void gemm_8p(
    const unsigned short* __restrict__ A, const unsigned short* __restrict__ B,
    float* __restrict__ Cf, long long sA, long long sB, long long sC,
    int K, int lda, int ldb, int ldc,
    unsigned short* __restrict__ u0, unsigned short* __restrict__ u1,
    unsigned short* __restrict__ u2,
    const float* __restrict__ f0, const float* __restrict__ f1,
    const float* __restrict__ f2,
    float* __restrict__ rsum, float scale)
{
  __shared__ unsigned short lds[2 * 32768];  // 128 KiB

  const int t = threadIdx.x;
  const int rowBase = blockIdx.y * 256;
  const int colBase = blockIdx.x * 256;
  A += (long long)blockIdx.z * sA;
  B += (long long)blockIdx.z * sB;

  const int l = t & 63;
  const int w = t >> 6;              // 0..7
  const int wrow = (w >> 2) * 128;   // 2 M-waves
  const int wcol = (w & 3) * 64;     // 4 N-waves
  const int q = l >> 4;
  const int r16 = l & 15;

  // staging geometry: per load-instr each wave covers 8 rows (1 KiB linear
  // LDS); thread t: row r0 = t>>3, slot t&7, global k-chunk = (t&7)^(r0&7).
  const int r0 = t >> 3;                        // 0..63
  const int goff = ((t & 7) ^ (r0 & 7)) << 3;

  f32x4 acc[8][4] = {};
  bf16x8 af[2][4], bfr[2][4];

  const int NT = K >> 6;   // 16 or 32 (always even)

  // prologue: stage K-tile 0 fully into buf0
  STAGE_A(0, 0, 0); STAGE_A(0, 1, 0);
  STAGE_B(0, 0, 0); STAGE_B(0, 1, 0);
  WAITV0; BARRIER();

  for (int kt2 = 0; kt2 < NT; kt2 += 2) {
    KTILE(kt2 * 64, 0, 32768, true);
    KTILE(kt2 * 64 + 64, 32768, 0, kt2 + 2 < NT);
  }

  // epilogues: C frag layout row=(lane>>4)*4+r, col=lane&15 (m89/m91)
  if (EPI == 1) {
    unsigned short* p16 = u0 + (long long)blockIdx.z * sC;
    float* rs = rsum + (long long)blockIdx.z * 2048;
#pragma unroll
    for (int i = 0; i < 8; i++) {
#pragma unroll
      for (int r = 0; r < 4; r++) {
        int row = rowBase + wrow + i * 16 + q * 4 + r;
        float rowpart = 0.f;
#pragma unroll
        for (int j = 0; j < 4; j++) {
          int col = colBase + wcol + j * 16 + r16;
          float e = __expf(acc[i][j][r] * scale);
          p16[(size_t)row * ldc + col] = f2bf(e);
          rowpart += e;
        }
#pragma unroll
        for (int m = 1; m < 16; m <<= 1) rowpart += __shfl_xor(rowpart, m);
        if (r16 == 0) atomicAdd(rs + row, rowpart);
      }
    }
  } else if (EPI == 2) {
    const int seg = colBase >> 10;  // block-uniform (256-tile never straddles)
    if (seg < 2) {
      unsigned short* dst = seg ? u1 : u0;
      const float* bias = seg ? f1 : f0;
      const int cb = colBase & 1023;
#pragma unroll
      for (int i = 0; i < 8; i++) {
#pragma unroll
        for (int r = 0; r < 4; r++) {
          int row = rowBase + wrow + i * 16 + q * 4 + r;
#pragma unroll
          for (int j = 0; j < 4; j++) {
            int col = cb + wcol + j * 16 + r16;
            dst[(size_t)row * 1024 + col] = f2bf(acc[i][j][r] + bias[col]);
          }
        }
      }
    } else {
      const int ob = colBase - 2048;
#pragma unroll
      for (int i = 0; i < 8; i++) {
        int posBase = rowBase + wrow + i * 16 + q * 4;
        int b = posBase >> 11;
        int pos = posBase & 2047;
#pragma unroll
        for (int j = 0; j < 4; j++) {
          int o = ob + wcol + j * 16 + r16;
          float bias = f2[o];
          ushort4 pk;
          pk.x = f2bf(acc[i][j][0] + bias);
          pk.y = f2bf(acc[i][j][1] + bias);
          pk.z = f2bf(acc[i][j][2] + bias);
          pk.w = f2bf(acc[i][j][3] + bias);
          *(ushort4*)(u2 + ((size_t)((b << 10) + o) * 2048 + pos)) = pk;
        }
      }
    }
  } else {  // EPI == 3
    float* C = Cf + (long long)blockIdx.z * sC;
    const float* rs = rsum + (long long)blockIdx.z * 2048;
#pragma unroll
    for (int i = 0; i < 8; i++) {
#pragma unroll
      for (int r = 0; r < 4; r++) {
        int row = rowBase + wrow + i * 16 + q * 4 + r;
        float inv = 1.0f / rs[row];
#pragma unroll
        for (int j = 0; j < 4; j++) {
          int col = colBase + wcol + j * 16 + r16;
          C[(size_t)row * ldc + col] = acc[i][j][r] * inv;
        }
      }
    }
  }
}

// ---------- fp32 -> bf16 cast (vectorized) + rsum zero-fill ----------

__global__ __launch_bounds__(256) void cast_f32_to_bf16(
    const float* __restrict__ in, unsigned short* __restrict__ out, int n4,
    float* __restrict__ rzero, int nz4)
{
  int i = blockIdx.x * 256 + threadIdx.x;
  if (i < nz4) ((float4*)rzero)[i] = make_float4(0.f, 0.f, 0.f, 0.f);
  if (i >= n4) return;
  float4 v = ((const float4*)in)[i];
  ushort4 o;
  o.x = f2bf(v.x); o.y = f2bf(v.y); o.z = f2bf(v.z); o.w = f2bf(v.w);
  ((ushort4*)out)[i] = o;
}

// ---------- W transpose: WT[z][h, d] = bf16(W_z[d, h]), 1024x1024, z=0..2 ----------

__global__ __launch_bounds__(256) void wtrans(
    const float* __restrict__ Wq, const float* __restrict__ Wk,
    const float* __restrict__ Wv, unsigned short* __restrict__ WT)
{
  __shared__ float tile[32][33];
  const float* in = blockIdx.z == 0 ? Wq : (blockIdx.z == 1 ? Wk : Wv);
  unsigned short* out = WT + (size_t)blockIdx.z * 1024 * 1024;
  const int bc = blockIdx.x * 32;  // h
  const int br = blockIdx.y * 32;  // d
  const int tx = threadIdx.x;
  const int ty = threadIdx.y;
#pragma unroll
  for (int i = 0; i < 4; i++)
    tile[ty + i * 8][tx] = in[(size_t)(br + ty + i * 8) * 1024 + bc + tx];
  __syncthreads();
#pragma unroll
  for (int i = 0; i < 4; i++)
    out[(size_t)(bc + ty + i * 8) * 1024 + br + tx] = f2bf(tile[tx][ty + i * 8]);
}

// ---------- driver ----------

extern "C" void kernel_launch(void* const* d_in, const int* in_sizes, int n_in,
                              void* d_out, int out_size, void* d_ws, size_t ws_size,
                              hipStream_t stream) {
  (void)in_sizes; (void)n_in; (void)out_size;

  const float* x  = (const float*)d_in[0];
  const float* Wq = (const float*)d_in[1];
  const float* bq = (const float*)d_in[2];
  const float* Wk = (const float*)d_in[3];
  const float* bk = (const float*)d_in[4];
  const float* Wv = (const float*)d_in[5];
  const float* bv = (const float*)d_in[6];
  float* out = (float*)d_out;

  const int Nb = 4, L = 2048, D = 1024, H = 1024, O = 1024;
  const int M = Nb * L;      // 8192
  const int NQKV = 3 * H;    // 3072

  char* ws = (char*)d_ws;
  size_t off = 0;
  unsigned short* xb = (unsigned short*)(ws + off); off += (size_t)M * D * 2;
  unsigned short* qb = (unsigned short*)(ws + off); off += (size_t)M * H * 2;
  unsigned short* kb = (unsigned short*)(ws + off); off += (size_t)M * H * 2;
  unsigned short* vt = (unsigned short*)(ws + off); off += (size_t)M * O * 2;
  unsigned short* WT = (unsigned short*)(ws + off); off += (size_t)NQKV * D * 2;
  unsigned short* P  = (unsigned short*)(ws + off); off += (size_t)Nb * L * L * 2;
  float* rsum = (float*)(ws + off); off += (size_t)Nb * L * 4;
  if (ws_size < off) return;

  dim3 blk256(256);
  dim3 blk512(512);

  // x -> bf16, and zero the row-sum accumulator (ws is poisoned every call)
  cast_f32_to_bf16<<<(M * D / 4 + 255) / 256, blk256, 0, stream>>>(
      x, xb, M * D / 4, rsum, Nb * L / 4);

  // WT = concat(Wq^T, Wk^T, Wv^T) as bf16 [3072, 1024] (one launch, z=3)
  wtrans<<<dim3(32, 32, 3), dim3(32, 8), 0, stream>>>(Wq, Wk, Wv, WT);

  // fused projections: q -> qb, k -> kb, v -> vt (transposed), + biases
  // grid 12x32 = 384 blocks (1.5 rounds of 256 CUs)
  gemm_8p<2><<<dim3(NQKV / 256, M / 256, 1), blk512, 0, stream>>>(
      xb, WT, nullptr, 0, 0, 0, D, D, D, 0,
      qb, kb, vt, bq, bk, bv, nullptr, 0.f);

  // QK + exp + row-sum atomics: P'[b] = exp(q k^T * scale)
  // grid 8x8x4 = 256 blocks (1.0 round)
  gemm_8p<1><<<dim3(L / 256, L / 256, Nb), blk512, 0, stream>>>(
      qb, kb, nullptr, (long long)L * H, (long long)L * H, (long long)L * L,
      H, H, H, L,
      P, nullptr, nullptr, nullptr, nullptr, nullptr,
      rsum, 0.022097086912079608f /* 1/sqrt(2048) */);

  // out[b] = (P'[b] @ vt[b]^T) / rsum
  // grid 4x8x4 = 128 blocks (0.5 round)
  gemm_8p<3><<<dim3(O / 256, L / 256, Nb), blk512, 0, stream>>>(
      P, vt, out, (long long)L * L, (long long)O * L, (long long)L * O,
      L, L, L, O,
      nullptr, nullptr, nullptr, nullptr, nullptr, nullptr,
      rsum, 0.f);
}

// Round 3
// 256.360 us; speedup vs baseline: 1.0302x; 1.0119x over previous
//
#include <hip/hip_runtime.h>
#include <hip/hip_bf16.h>

// ---------- helpers ----------

typedef __attribute__((ext_vector_type(8))) short bf16x8;
typedef __attribute__((ext_vector_type(4))) float f32x4;

#define AS_G(p) ((__attribute__((address_space(1))) void*)(p))
#define AS_L(p) ((__attribute__((address_space(3))) void*)(p))

__device__ __forceinline__ unsigned short f2bf(float f) {
  unsigned int u = __float_as_uint(f);
  unsigned int lsb = (u >> 16) & 1u;
  u += 0x7fffu + lsb;
  return (unsigned short)(u >> 16);
}

#define WAITV(n) asm volatile("s_waitcnt vmcnt(" #n ")" ::: "memory")
#define BARRIER() do { __builtin_amdgcn_s_barrier(); asm volatile("" ::: "memory"); } while (0)

// ---------- 256x256 8-phase NT GEMM with COUNTED vmcnt (m201/m218 schedule) ----------
// A[m,k] lda, B[n,k] ldb, bf16, K-contiguous. BM=BN=256, BK=64.
// 512 threads = 8 waves (2M x 4N); per-wave C 128x64 (8x4 frags 16x16),
// acc[8][4]. LDS = 2 buffers x (A 256x64 + B 256x64) = 128 KiB.
// Swizzle (measured 0 SQ_LDS_BANK_CONFLICT): row = 8 chunks of 8 elems (16B);
// slot s of row r holds k-chunk s ^ (r&7); staging pre-swizzles the GLOBAL
// source so the LDS dest stays linear (global_load_lds requirement).
//
// Per K-tile: 4 phases = C quadrants (0,0)(0,1)(1,1)(1,0), 16 MFMA each,
// register reuse -> ds_reads/phase = 12/4/8/0. Staging of tile t+2 goes into
// the SAME buffer as tile t, into regions proven free by the phase order:
//   A q0,q2 (rows 0-63,128-191) last read p1 -> staged p2 (2 loads)
//   B (all)                     last read p2 -> staged p3 (4 loads)
//   A q1,q3 (rows 64-127,192-255) last read p3 -> staged p4 (2 loads)
// ONE s_waitcnt vmcnt(8) per tile, at end of p4 after the MFMA cluster:
// keeps tile t+2's 8 loads in flight across the next 8 barriers; drains
// tile t+1's 8 (issued a full tile ~2700cyc ago -> wait ~free). vmcnt never
// reaches 0 in the main loop (m218: counted-vs-drain0 = +38..73%). Only the
// peeled last iteration drains fully.
//
// EPI=1: QK epilogue: P' = bf16(exp(acc*scale)) (unnormalized softmax
//        numerator; |acc*scale| small by construction) + fp32 atomic
//        row-sum into rsum.
// EPI=2: QKV projection split: col seg 0 -> qb (+bq), seg 1 -> kb (+bk),
//        seg 2 -> vt TRANSPOSED (+bv) as ushort4.
// EPI=3: PV epilogue: out fp32 = acc / rsum[row].

// stage one 64-row block (1 global_load_lds per thread, 512thr x 16B = 8KB)
#define S64A(ktk, rb, bofs)                                                   \
  __builtin_amdgcn_global_load_lds(                                           \
      AS_G(A + (size_t)(rowBase + (rb) * 64 + r0) * lda + (ktk) + goff),      \
      AS_L(lds + (bofs) + (rb) * 4096 + t * 8), 16, 0, 0)

#define S64B(ktk, rb, bofs)                                                   \
  __builtin_amdgcn_global_load_lds(                                           \
      AS_G(B + (size_t)(colBase + (rb) * 64 + r0) * ldb + (ktk) + goff),      \
      AS_L(lds + (bofs) + 16384 + (rb) * 4096 + t * 8), 16, 0, 0)

#define STAGE_TILE(ktk, bofs) do {                                            \
    S64A(ktk, 0, bofs); S64A(ktk, 1, bofs);                                   \
    S64A(ktk, 2, bofs); S64A(ktk, 3, bofs);                                   \
    S64B(ktk, 0, bofs); S64B(ktk, 1, bofs);                                   \
    S64B(ktk, 2, bofs); S64B(ktk, 3, bofs); } while (0)

#define LOAD_A(ih, bofs) do { _Pragma("unroll")                               \
    for (int ks_ = 0; ks_ < 2; ks_++) { _Pragma("unroll")                     \
      for (int ii = 0; ii < 4; ii++) {                                        \
        int row_ = wrow + ((ih) * 4 + ii) * 16 + r16;                         \
        int slot_ = (ks_ * 4 + q) ^ (r16 & 7);                                \
        af[ks_][ii] = *(const bf16x8*)(lds + (bofs) + row_ * 64 + slot_ * 8); \
      } } } while (0)

#define LOAD_B(jh, bofs) do { _Pragma("unroll")                               \
    for (int ks_ = 0; ks_ < 2; ks_++) { _Pragma("unroll")                     \
      for (int jj = 0; jj < 2; jj++) {                                        \
        int row_ = wcol + ((jh) * 2 + jj) * 16 + r16;                         \
        int slot_ = (ks_ * 4 + q) ^ (r16 & 7);                                \
        bfr[ks_][(jh) * 2 + jj] =                                             \
            *(const bf16x8*)(lds + (bofs) + 16384 + row_ * 64 + slot_ * 8);   \
      } } } while (0)

#define MM(ih, jh) do { __builtin_amdgcn_s_setprio(1); _Pragma("unroll")      \
    for (int ks_ = 0; ks_ < 2; ks_++) { _Pragma("unroll")                     \
      for (int ii = 0; ii < 4; ii++) { _Pragma("unroll")                      \
        for (int jj = 0; jj < 2; jj++)                                        \
          acc[(ih) * 4 + ii][(jh) * 2 + jj] =                                 \
              __builtin_amdgcn_mfma_f32_16x16x32_bf16(                        \
                  af[ks_][ii], bfr[ks_][(jh) * 2 + jj],                       \
                  acc[(ih) * 4 + ii][(jh) * 2 + jj], 0, 0, 0);                \
      } }                                                                     \
    __builtin_amdgcn_s_setprio(0); } while (0)

// One K-tile = 4 phases x {reads/stages ; barrier ; MFMA ; barrier}.
// ST is a compile-time 0/1: stage tile (ktc+128) into the same buffer.
#define KTILE(ktc, bofs, ST) do {                                             \
    /* p1 (0,0): 12 ds_reads */                                               \
    LOAD_A(0, bofs); LOAD_B(0, bofs);                                         \
    BARRIER(); MM(0, 0); BARRIER();                                           \
    /* p2 (0,1): 4 ds + stage A q0,q2 (freed by p1) */                        \
    LOAD_B(1, bofs);                                                          \
    if (ST) { S64A((ktc) + 128, 0, bofs); S64A((ktc) + 128, 2, bofs); }       \
    BARRIER(); MM(0, 1); BARRIER();                                           \
    /* p3 (1,1): 8 ds + stage B q0-q3 (freed by p2) */                        \
    LOAD_A(1, bofs);                                                          \
    if (ST) { S64B((ktc) + 128, 0, bofs); S64B((ktc) + 128, 1, bofs);         \
              S64B((ktc) + 128, 2, bofs); S64B((ktc) + 128, 3, bofs); }       \
    BARRIER(); MM(1, 1); BARRIER();                                           \
    /* p4 (1,0): stage A q1,q3 (freed by p3); counted wait AFTER MFMA */      \
    if (ST) { S64A((ktc) + 128, 1, bofs); S64A((ktc) + 128, 3, bofs); }       \
    BARRIER(); MM(1, 0);                                                      \
    if (ST) { WAITV(8); } else { WAITV(0); }                                  \
    BARRIER(); } while (0)

template <int EPI>
__global__ __launch_bounds__(512, 2) void gemm_8p(
    const unsigned short* __restrict__ A, const unsigned short* __restrict__ B,
    float* __restrict__ Cf, long long sA, long long sB, long long sC,
    int K, int lda, int ldb, int ldc,
    unsigned short* __restrict__ u0, unsigned short* __restrict__ u1,
    unsigned short* __restrict__ u2,
    const float* __restrict__ f0, const float* __restrict__ f1,
    const float* __restrict__ f2,
    float* __restrict__ rsum, float scale)
{
  __shared__ unsigned short lds[2 * 32768];  // 128 KiB

  const int t = threadIdx.x;
  const int rowBase = blockIdx.y * 256;
  const int colBase = blockIdx.x * 256;
  A += (long long)blockIdx.z * sA;
  B += (long long)blockIdx.z * sB;

  const int l = t & 63;
  const int w = t >> 6;              // 0..7
  const int wrow = (w >> 2) * 128;   // 2 M-waves
  const int wcol = (w & 3) * 64;     // 4 N-waves
  const int q = l >> 4;
  const int r16 = l & 15;

  // staging geometry: thread t covers row r0 = t>>3 (of a 64-row block),
  // slot t&7, global k-chunk = (t&7)^(r0&7) (pre-swizzled source).
  const int r0 = t >> 3;                        // 0..63
  const int goff = ((t & 7) ^ (r0 & 7)) << 3;

  f32x4 acc[8][4] = {};
  bf16x8 af[2][4], bfr[2][4];

  // prologue: tile0 -> buf0, tile1 -> buf1; drain tile0 only (tile1 stays
  // in flight, drained by the first in-loop vmcnt(8)).
  STAGE_TILE(0, 0);
  STAGE_TILE(64, 32768);
  WAITV(8);
  BARRIER();

  // main loop: all iterations except the last stage 2 tiles ahead.
  int kt = 0;
  for (; kt + 128 < K; kt += 128) {
    KTILE(kt, 0, 1);
    KTILE(kt + 64, 32768, 1);
  }
  KTILE(kt, 0, 0);
  KTILE(kt + 64, 32768, 0);

  // epilogues: C frag layout row=(lane>>4)*4+r, col=lane&15 (m89/m91)
  if (EPI == 1) {
    unsigned short* p16 = u0 + (long long)blockIdx.z * sC;
    float* rs = rsum + (long long)blockIdx.z * 2048;
#pragma unroll
    for (int i = 0; i < 8; i++) {
#pragma unroll
      for (int r = 0; r < 4; r++) {
        int row = rowBase + wrow + i * 16 + q * 4 + r;
        float rowpart = 0.f;
#pragma unroll
        for (int j = 0; j < 4; j++) {
          int col = colBase + wcol + j * 16 + r16;
          float e = __expf(acc[i][j][r] * scale);
          p16[(size_t)row * ldc + col] = f2bf(e);
          rowpart += e;
        }
#pragma unroll
        for (int m = 1; m < 16; m <<= 1) rowpart += __shfl_xor(rowpart, m);
        if (r16 == 0) atomicAdd(rs + row, rowpart);
      }
    }
  } else if (EPI == 2) {
    const int seg = colBase >> 10;  // block-uniform (256-tile never straddles)
    if (seg < 2) {
      unsigned short* dst = seg ? u1 : u0;
      const float* bias = seg ? f1 : f0;
      const int cb = colBase & 1023;
#pragma unroll
      for (int i = 0; i < 8; i++) {
#pragma unroll
        for (int r = 0; r < 4; r++) {
          int row = rowBase + wrow + i * 16 + q * 4 + r;
#pragma unroll
          for (int j = 0; j < 4; j++) {
            int col = cb + wcol + j * 16 + r16;
            dst[(size_t)row * 1024 + col] = f2bf(acc[i][j][r] + bias[col]);
          }
        }
      }
    } else {
      const int ob = colBase - 2048;
#pragma unroll
      for (int i = 0; i < 8; i++) {
        int posBase = rowBase + wrow + i * 16 + q * 4;
        int b = posBase >> 11;
        int pos = posBase & 2047;
#pragma unroll
        for (int j = 0; j < 4; j++) {
          int o = ob + wcol + j * 16 + r16;
          float bias = f2[o];
          ushort4 pk;
          pk.x = f2bf(acc[i][j][0] + bias);
          pk.y = f2bf(acc[i][j][1] + bias);
          pk.z = f2bf(acc[i][j][2] + bias);
          pk.w = f2bf(acc[i][j][3] + bias);
          *(ushort4*)(u2 + ((size_t)((b << 10) + o) * 2048 + pos)) = pk;
        }
      }
    }
  } else {  // EPI == 3
    float* C = Cf + (long long)blockIdx.z * sC;
    const float* rs = rsum + (long long)blockIdx.z * 2048;
#pragma unroll
    for (int i = 0; i < 8; i++) {
#pragma unroll
      for (int r = 0; r < 4; r++) {
        int row = rowBase + wrow + i * 16 + q * 4 + r;
        float inv = 1.0f / rs[row];
#pragma unroll
        for (int j = 0; j < 4; j++) {
          int col = colBase + wcol + j * 16 + r16;
          C[(size_t)row * ldc + col] = acc[i][j][r] * inv;
        }
      }
    }
  }
}

// ---------- fp32 -> bf16 cast (vectorized) + rsum zero-fill ----------

__global__ __launch_bounds__(256) void cast_f32_to_bf16(
    const float* __restrict__ in, unsigned short* __restrict__ out, int n4,
    float* __restrict__ rzero, int nz4)
{
  int i = blockIdx.x * 256 + threadIdx.x;
  if (i < nz4) ((float4*)rzero)[i] = make_float4(0.f, 0.f, 0.f, 0.f);
  if (i >= n4) return;
  float4 v = ((const float4*)in)[i];
  ushort4 o;
  o.x = f2bf(v.x); o.y = f2bf(v.y); o.z = f2bf(v.z); o.w = f2bf(v.w);
  ((ushort4*)out)[i] = o;
}

// ---------- W transpose: WT[z][h, d] = bf16(W_z[d, h]), 1024x1024, z=0..2 ----------

__global__ __launch_bounds__(256) void wtrans(
    const float* __restrict__ Wq, const float* __restrict__ Wk,
    const float* __restrict__ Wv, unsigned short* __restrict__ WT)
{
  __shared__ float tile[32][33];
  const float* in = blockIdx.z == 0 ? Wq : (blockIdx.z == 1 ? Wk : Wv);
  unsigned short* out = WT + (size_t)blockIdx.z * 1024 * 1024;
  const int bc = blockIdx.x * 32;  // h
  const int br = blockIdx.y * 32;  // d
  const int tx = threadIdx.x;
  const int ty = threadIdx.y;
#pragma unroll
  for (int i = 0; i < 4; i++)
    tile[ty + i * 8][tx] = in[(size_t)(br + ty + i * 8) * 1024 + bc + tx];
  __syncthreads();
#pragma unroll
  for (int i = 0; i < 4; i++)
    out[(size_t)(bc + ty + i * 8) * 1024 + br + tx] = f2bf(tile[tx][ty + i * 8]);
}

// ---------- driver ----------

extern "C" void kernel_launch(void* const* d_in, const int* in_sizes, int n_in,
                              void* d_out, int out_size, void* d_ws, size_t ws_size,
                              hipStream_t stream) {
  (void)in_sizes; (void)n_in; (void)out_size;

  const float* x  = (const float*)d_in[0];
  const float* Wq = (const float*)d_in[1];
  const float* bq = (const float*)d_in[2];
  const float* Wk = (const float*)d_in[3];
  const float* bk = (const float*)d_in[4];
  const float* Wv = (const float*)d_in[5];
  const float* bv = (const float*)d_in[6];
  float* out = (float*)d_out;

  const int Nb = 4, L = 2048, D = 1024, H = 1024, O = 1024;
  const int M = Nb * L;      // 8192
  const int NQKV = 3 * H;    // 3072

  char* ws = (char*)d_ws;
  size_t off = 0;
  unsigned short* xb = (unsigned short*)(ws + off); off += (size_t)M * D * 2;
  unsigned short* qb = (unsigned short*)(ws + off); off += (size_t)M * H * 2;
  unsigned short* kb = (unsigned short*)(ws + off); off += (size_t)M * H * 2;
  unsigned short* vt = (unsigned short*)(ws + off); off += (size_t)M * O * 2;
  unsigned short* WT = (unsigned short*)(ws + off); off += (size_t)NQKV * D * 2;
  unsigned short* P  = (unsigned short*)(ws + off); off += (size_t)Nb * L * L * 2;
  float* rsum = (float*)(ws + off); off += (size_t)Nb * L * 4;
  if (ws_size < off) return;

  dim3 blk256(256);
  dim3 blk512(512);

  // x -> bf16, and zero the row-sum accumulator (ws is poisoned every call)
  cast_f32_to_bf16<<<(M * D / 4 + 255) / 256, blk256, 0, stream>>>(
      x, xb, M * D / 4, rsum, Nb * L / 4);

  // WT = concat(Wq^T, Wk^T, Wv^T) as bf16 [3072, 1024] (one launch, z=3)
  wtrans<<<dim3(32, 32, 3), dim3(32, 8), 0, stream>>>(Wq, Wk, Wv, WT);

  // fused projections: q -> qb, k -> kb, v -> vt (transposed), + biases
  // grid 12x32 = 384 blocks (1.5 rounds -- known quantization waste)
  gemm_8p<2><<<dim3(NQKV / 256, M / 256, 1), blk512, 0, stream>>>(
      xb, WT, nullptr, 0, 0, 0, D, D, D, 0,
      qb, kb, vt, bq, bk, bv, nullptr, 0.f);

  // QK + exp + row-sum atomics: P'[b] = exp(q k^T * scale)
  // grid 8x8x4 = 256 blocks (1.0 round)
  gemm_8p<1><<<dim3(L / 256, L / 256, Nb), blk512, 0, stream>>>(
      qb, kb, nullptr, (long long)L * H, (long long)L * H, (long long)L * L,
      H, H, H, L,
      P, nullptr, nullptr, nullptr, nullptr, nullptr,
      rsum, 0.022097086912079608f /* 1/sqrt(2048) */);

  // out[b] = (P'[b] @ vt[b]^T) / rsum
  // grid 4x8x4 = 128 blocks (0.5 round -- known quantization waste)
  gemm_8p<3><<<dim3(O / 256, L / 256, Nb), blk512, 0, stream>>>(
      P, vt, out, (long long)L * L, (long long)O * L, (long long)L * O,
      L, L, L, O,
      nullptr, nullptr, nullptr, nullptr, nullptr, nullptr,
      rsum, 0.f);
}

// Round 4
// 253.048 us; speedup vs baseline: 1.0437x; 1.0131x over previous
//
#include <hip/hip_runtime.h>
#include <hip/hip_bf16.h>

// ---------- helpers ----------

typedef __attribute__((ext_vector_type(8))) short bf16x8;
typedef __attribute__((ext_vector_type(4))) float f32x4;

#define AS_G(p) ((__attribute__((address_space(1))) void*)(p))
#define AS_L(p) ((__attribute__((address_space(3))) void*)(p))

__device__ __forceinline__ unsigned short f2bf(float f) {
  unsigned int u = __float_as_uint(f);
  unsigned int lsb = (u >> 16) & 1u;
  u += 0x7fffu + lsb;
  return (unsigned short)(u >> 16);
}

#define WAITV(n) asm volatile("s_waitcnt vmcnt(" #n ")" ::: "memory")
// Fenced barrier + sched pin: plain LDS loads/stores and gload_lds cannot
// cross (asm "memory" both sides); sched_barrier(0) stops register-only MFMA
// from floating across the region boundary (rule #18/#19).
#define BARRIER() do { asm volatile("" ::: "memory");                         \
    __builtin_amdgcn_s_barrier();                                             \
    asm volatile("" ::: "memory");                                            \
    __builtin_amdgcn_sched_barrier(0); } while (0)

// ---------- 256x256 2-region NT GEMM, counted vmcnt, reads hidden under MFMA ----------
// A[m,k] lda, B[n,k] ldb, bf16, K-contiguous. BM=BN=256, BK=64.
// 512 threads = 8 waves (2M x 4N); per-wave C 128x64 (8x4 frags 16x16),
// acc[8][4] (128 AGPR). LDS = 2 buffers x (A 256x64 + B 256x64) = 128 KiB.
// Swizzle (measured 0 SQ_LDS_BANK_CONFLICT): row = 8 chunks of 8 elems (16B);
// slot s of row r holds k-chunk s ^ (r&7); staging pre-swizzles the GLOBAL
// source so the LDS dest stays linear (global_load_lds requirement).
//
// R3 post-mortem: 4 lockstep phases x [read-burst; barrier; MFMA; barrier]
// alternate the LDS and MFMA pipes -> ~5460 cyc/tile, MfmaUtil 27%, nothing
// >30% busy. R4: TWO regions/tile, ds_reads issued at region top service
// UNDER the 32-MFMA cluster (first MFMA gates on lgkmcnt(4), not a full
// drain); 2 barriers/tile instead of 8.
//   R1: reads A-ih0(8)+B-all(8); carry-stage A q1,q3 of tile t+1 -> other
//       buffer (tail of t-1's stage set); MM(0,0)+MM(0,1).
//   R2: reads A-ih1(8); six-stage tile t+2 -> THIS buffer (A q0,q2 + B all,
//       freed by R1's read-issues, ordered by the R1->R2 barrier);
//       MM(1,1)+MM(1,0); vmcnt(6); barrier.
// vmcnt(6) at tile end drains exactly buf(t+1)'s stage set (t-1's six + t's
// carry, oldest-first per m135) while keeping t's six (6 loads) in flight --
// never drains to 0 in steady state (m218). WAR audit: A q0,q2 + B read-issue
// in R1, staged in R2 (barrier-ordered); A q1,q3 read-issue in R2, staged in
// t+1's R1 (tile-end barrier); R2 reads (q1,q3) disjoint from R2 writes
// (q0,q2 + B). RAW: buf(t) completion guaranteed by t-1's vmcnt(6).
//
// EPI=1: QK epilogue: P' = bf16(exp(acc*scale)) (unnormalized softmax
//        numerator; |acc*scale| small by construction) + fp32 atomic
//        row-sum into rsum.
// EPI=2: QKV projection split: col seg 0 -> qb (+bq), seg 1 -> kb (+bk),
//        seg 2 -> vt TRANSPOSED (+bv) as ushort4.
// EPI=3: PV epilogue: out fp32 = acc / rsum[row].

// stage one 64-row block (1 global_load_lds per thread, 512thr x 16B = 8KB)
#define S64A(ktk, rb, bofs)                                                   \
  __builtin_amdgcn_global_load_lds(                                           \
      AS_G(A + (size_t)(rowBase + (rb) * 64 + r0) * lda + (ktk) + goff),      \
      AS_L(lds + (bofs) + (rb) * 4096 + t * 8), 16, 0, 0)

#define S64B(ktk, rb, bofs)                                                   \
  __builtin_amdgcn_global_load_lds(                                           \
      AS_G(B + (size_t)(colBase + (rb) * 64 + r0) * ldb + (ktk) + goff),      \
      AS_L(lds + (bofs) + 16384 + (rb) * 4096 + t * 8), 16, 0, 0)

#define STAGE_TILE(ktk, bofs) do {                                            \
    S64A(ktk, 0, bofs); S64A(ktk, 1, bofs);                                   \
    S64A(ktk, 2, bofs); S64A(ktk, 3, bofs);                                   \
    S64B(ktk, 0, bofs); S64B(ktk, 1, bofs);                                   \
    S64B(ktk, 2, bofs); S64B(ktk, 3, bofs); } while (0)

#define LOAD_A(ih, bofs) do { _Pragma("unroll")                               \
    for (int ks_ = 0; ks_ < 2; ks_++) { _Pragma("unroll")                     \
      for (int ii = 0; ii < 4; ii++) {                                        \
        int row_ = wrow + ((ih) * 4 + ii) * 16 + r16;                         \
        int slot_ = (ks_ * 4 + q) ^ (r16 & 7);                                \
        af[ks_][ii] = *(const bf16x8*)(lds + (bofs) + row_ * 64 + slot_ * 8); \
      } } } while (0)

#define LOAD_B(jh, bofs) do { _Pragma("unroll")                               \
    for (int ks_ = 0; ks_ < 2; ks_++) { _Pragma("unroll")                     \
      for (int jj = 0; jj < 2; jj++) {                                        \
        int row_ = wcol + ((jh) * 2 + jj) * 16 + r16;                         \
        int slot_ = (ks_ * 4 + q) ^ (r16 & 7);                                \
        bfr[ks_][(jh) * 2 + jj] =                                             \
            *(const bf16x8*)(lds + (bofs) + 16384 + row_ * 64 + slot_ * 8);   \
      } } } while (0)

#define MM(ih, jh) do { __builtin_amdgcn_s_setprio(1); _Pragma("unroll")      \
    for (int ks_ = 0; ks_ < 2; ks_++) { _Pragma("unroll")                     \
      for (int ii = 0; ii < 4; ii++) { _Pragma("unroll")                      \
        for (int jj = 0; jj < 2; jj++)                                        \
          acc[(ih) * 4 + ii][(jh) * 2 + jj] =                                 \
              __builtin_amdgcn_mfma_f32_16x16x32_bf16(                        \
                  af[ks_][ii], bfr[ks_][(jh) * 2 + jj],                       \
                  acc[(ih) * 4 + ii][(jh) * 2 + jj], 0, 0, 0);                \
      } }                                                                     \
    __builtin_amdgcn_s_setprio(0); } while (0)

// One K-tile = 2 regions (see header comment).
#define TILE(ktc, bofs, obofs) do {                                           \
    /* R1 */                                                                  \
    LOAD_A(0, bofs); LOAD_B(0, bofs); LOAD_B(1, bofs);                        \
    if ((ktc) && (ktc) + 64 < K) {                                            \
      S64A((ktc) + 64, 1, obofs); S64A((ktc) + 64, 3, obofs);                 \
    }                                                                         \
    MM(0, 0); MM(0, 1);                                                       \
    BARRIER();                                                                \
    /* R2 */                                                                  \
    LOAD_A(1, bofs);                                                          \
    if ((ktc) + 128 < K) {                                                    \
      S64A((ktc) + 128, 0, bofs); S64A((ktc) + 128, 2, bofs);                 \
      S64B((ktc) + 128, 0, bofs); S64B((ktc) + 128, 1, bofs);                 \
      S64B((ktc) + 128, 2, bofs); S64B((ktc) + 128, 3, bofs);                 \
    }                                                                         \
    MM(1, 1); MM(1, 0);                                                       \
    if ((ktc) + 128 < K) { WAITV(6); } else { WAITV(0); }                     \
    BARRIER(); } while (0)

template <int EPI>
__global__ __launch_bounds__(512, 2) void gemm_2r(
    const unsigned short* __restrict__ A, const unsigned short* __restrict__ B,
    float* __restrict__ Cf, long long sA, long long sB, long long sC,
    int K, int lda, int ldb, int ldc,
    unsigned short* __restrict__ u0, unsigned short* __restrict__ u1,
    unsigned short* __restrict__ u2,
    const float* __restrict__ f0, const float* __restrict__ f1,
    const float* __restrict__ f2,
    float* __restrict__ rsum, float scale)
{
  __shared__ unsigned short lds[2 * 32768];  // 128 KiB

  const int t = threadIdx.x;
  const int rowBase = blockIdx.y * 256;
  const int colBase = blockIdx.x * 256;
  A += (long long)blockIdx.z * sA;
  B += (long long)blockIdx.z * sB;

  const int l = t & 63;
  const int w = t >> 6;              // 0..7
  const int wrow = (w >> 2) * 128;   // 2 M-waves
  const int wcol = (w & 3) * 64;     // 4 N-waves
  const int q = l >> 4;
  const int r16 = l & 15;

  // staging geometry: thread t covers row r0 = t>>3 (of a 64-row block),
  // slot t&7, global k-chunk = (t&7)^(r0&7) (pre-swizzled source).
  const int r0 = t >> 3;                        // 0..63
  const int goff = ((t & 7) ^ (r0 & 7)) << 3;

  f32x4 acc[8][4] = {};
  bf16x8 af[2][4], bfr[2][4];

  // prologue: tile0 -> buf0, tile1 -> buf1; drain tile0 only (tile1's 8
  // stay in flight, drained by tile0's in-loop vmcnt(6)).
  STAGE_TILE(0, 0);
  STAGE_TILE(64, 32768);
  WAITV(8);
  BARRIER();

  for (int kt = 0; kt < K; kt += 128) {   // K is a multiple of 128
    TILE(kt, 0, 32768);
    TILE(kt + 64, 32768, 0);
  }

  // epilogues: C frag layout row=(lane>>4)*4+r, col=lane&15 (m89/m91)
  if (EPI == 1) {
    unsigned short* p16 = u0 + (long long)blockIdx.z * sC;
    float* rs = rsum + (long long)blockIdx.z * 2048;
#pragma unroll
    for (int i = 0; i < 8; i++) {
#pragma unroll
      for (int r = 0; r < 4; r++) {
        int row = rowBase + wrow + i * 16 + q * 4 + r;
        float rowpart = 0.f;
#pragma unroll
        for (int j = 0; j < 4; j++) {
          int col = colBase + wcol + j * 16 + r16;
          float e = __expf(acc[i][j][r] * scale);
          p16[(size_t)row * ldc + col] = f2bf(e);
          rowpart += e;
        }
#pragma unroll
        for (int m = 1; m < 16; m <<= 1) rowpart += __shfl_xor(rowpart, m);
        if (r16 == 0) atomicAdd(rs + row, rowpart);
      }
    }
  } else if (EPI == 2) {
    const int seg = colBase >> 10;  // block-uniform (256-tile never straddles)
    if (seg < 2) {
      unsigned short* dst = seg ? u1 : u0;
      const float* bias = seg ? f1 : f0;
      const int cb = colBase & 1023;
#pragma unroll
      for (int i = 0; i < 8; i++) {
#pragma unroll
        for (int r = 0; r < 4; r++) {
          int row = rowBase + wrow + i * 16 + q * 4 + r;
#pragma unroll
          for (int j = 0; j < 4; j++) {
            int col = cb + wcol + j * 16 + r16;
            dst[(size_t)row * 1024 + col] = f2bf(acc[i][j][r] + bias[col]);
          }
        }
      }
    } else {
      const int ob = colBase - 2048;
#pragma unroll
      for (int i = 0; i < 8; i++) {
        int posBase = rowBase + wrow + i * 16 + q * 4;
        int b = posBase >> 11;
        int pos = posBase & 2047;
#pragma unroll
        for (int j = 0; j < 4; j++) {
          int o = ob + wcol + j * 16 + r16;
          float bias = f2[o];
          ushort4 pk;
          pk.x = f2bf(acc[i][j][0] + bias);
          pk.y = f2bf(acc[i][j][1] + bias);
          pk.z = f2bf(acc[i][j][2] + bias);
          pk.w = f2bf(acc[i][j][3] + bias);
          *(ushort4*)(u2 + ((size_t)((b << 10) + o) * 2048 + pos)) = pk;
        }
      }
    }
  } else {  // EPI == 3
    float* C = Cf + (long long)blockIdx.z * sC;
    const float* rs = rsum + (long long)blockIdx.z * 2048;
#pragma unroll
    for (int i = 0; i < 8; i++) {
#pragma unroll
      for (int r = 0; r < 4; r++) {
        int row = rowBase + wrow + i * 16 + q * 4 + r;
        float inv = 1.0f / rs[row];
#pragma unroll
        for (int j = 0; j < 4; j++) {
          int col = colBase + wcol + j * 16 + r16;
          C[(size_t)row * ldc + col] = acc[i][j][r] * inv;
        }
      }
    }
  }
}

// ---------- fp32 -> bf16 cast (vectorized) + rsum zero-fill ----------

__global__ __launch_bounds__(256) void cast_f32_to_bf16(
    const float* __restrict__ in, unsigned short* __restrict__ out, int n4,
    float* __restrict__ rzero, int nz4)
{
  int i = blockIdx.x * 256 + threadIdx.x;
  if (i < nz4) ((float4*)rzero)[i] = make_float4(0.f, 0.f, 0.f, 0.f);
  if (i >= n4) return;
  float4 v = ((const float4*)in)[i];
  ushort4 o;
  o.x = f2bf(v.x); o.y = f2bf(v.y); o.z = f2bf(v.z); o.w = f2bf(v.w);
  ((ushort4*)out)[i] = o;
}

// ---------- W transpose: WT[z][h, d] = bf16(W_z[d, h]), 1024x1024, z=0..2 ----------

__global__ __launch_bounds__(256) void wtrans(
    const float* __restrict__ Wq, const float* __restrict__ Wk,
    const float* __restrict__ Wv, unsigned short* __restrict__ WT)
{
  __shared__ float tile[32][33];
  const float* in = blockIdx.z == 0 ? Wq : (blockIdx.z == 1 ? Wk : Wv);
  unsigned short* out = WT + (size_t)blockIdx.z * 1024 * 1024;
  const int bc = blockIdx.x * 32;  // h
  const int br = blockIdx.y * 32;  // d
  const int tx = threadIdx.x;
  const int ty = threadIdx.y;
#pragma unroll
  for (int i = 0; i < 4; i++)
    tile[ty + i * 8][tx] = in[(size_t)(br + ty + i * 8) * 1024 + bc + tx];
  __syncthreads();
#pragma unroll
  for (int i = 0; i < 4; i++)
    out[(size_t)(bc + ty + i * 8) * 1024 + br + tx] = f2bf(tile[tx][ty + i * 8]);
}

// ---------- driver ----------

extern "C" void kernel_launch(void* const* d_in, const int* in_sizes, int n_in,
                              void* d_out, int out_size, void* d_ws, size_t ws_size,
                              hipStream_t stream) {
  (void)in_sizes; (void)n_in; (void)out_size;

  const float* x  = (const float*)d_in[0];
  const float* Wq = (const float*)d_in[1];
  const float* bq = (const float*)d_in[2];
  const float* Wk = (const float*)d_in[3];
  const float* bk = (const float*)d_in[4];
  const float* Wv = (const float*)d_in[5];
  const float* bv = (const float*)d_in[6];
  float* out = (float*)d_out;

  const int Nb = 4, L = 2048, D = 1024, H = 1024, O = 1024;
  const int M = Nb * L;      // 8192
  const int NQKV = 3 * H;    // 3072

  char* ws = (char*)d_ws;
  size_t off = 0;
  unsigned short* xb = (unsigned short*)(ws + off); off += (size_t)M * D * 2;
  unsigned short* qb = (unsigned short*)(ws + off); off += (size_t)M * H * 2;
  unsigned short* kb = (unsigned short*)(ws + off); off += (size_t)M * H * 2;
  unsigned short* vt = (unsigned short*)(ws + off); off += (size_t)M * O * 2;
  unsigned short* WT = (unsigned short*)(ws + off); off += (size_t)NQKV * D * 2;
  unsigned short* P  = (unsigned short*)(ws + off); off += (size_t)Nb * L * L * 2;
  float* rsum = (float*)(ws + off); off += (size_t)Nb * L * 4;
  if (ws_size < off) return;

  dim3 blk256(256);
  dim3 blk512(512);

  // x -> bf16, and zero the row-sum accumulator (ws is poisoned every call)
  cast_f32_to_bf16<<<(M * D / 4 + 255) / 256, blk256, 0, stream>>>(
      x, xb, M * D / 4, rsum, Nb * L / 4);

  // WT = concat(Wq^T, Wk^T, Wv^T) as bf16 [3072, 1024] (one launch, z=3)
  wtrans<<<dim3(32, 32, 3), dim3(32, 8), 0, stream>>>(Wq, Wk, Wv, WT);

  // fused projections: q -> qb, k -> kb, v -> vt (transposed), + biases
  // grid 12x32 = 384 blocks (1.5 rounds -- quantization fix deferred)
  gemm_2r<2><<<dim3(NQKV / 256, M / 256, 1), blk512, 0, stream>>>(
      xb, WT, nullptr, 0, 0, 0, D, D, D, 0,
      qb, kb, vt, bq, bk, bv, nullptr, 0.f);

  // QK + exp + row-sum atomics: P'[b] = exp(q k^T * scale)
  // grid 8x8x4 = 256 blocks (1.0 round)
  gemm_2r<1><<<dim3(L / 256, L / 256, Nb), blk512, 0, stream>>>(
      qb, kb, nullptr, (long long)L * H, (long long)L * H, (long long)L * L,
      H, H, H, L,
      P, nullptr, nullptr, nullptr, nullptr, nullptr,
      rsum, 0.022097086912079608f /* 1/sqrt(2048) */);

  // out[b] = (P'[b] @ vt[b]^T) / rsum
  // grid 4x8x4 = 128 blocks (0.5 round -- quantization fix deferred)
  gemm_2r<3><<<dim3(O / 256, L / 256, Nb), blk512, 0, stream>>>(
      P, vt, out, (long long)L * L, (long long)O * L, (long long)L * O,
      L, L, L, O,
      nullptr, nullptr, nullptr, nullptr, nullptr, nullptr,
      rsum, 0.f);
}

// Round 5
// 247.812 us; speedup vs baseline: 1.0657x; 1.0211x over previous
//
#include <hip/hip_runtime.h>
#include <hip/hip_bf16.h>

// ---------- helpers ----------

typedef __attribute__((ext_vector_type(8))) short bf16x8;
typedef __attribute__((ext_vector_type(4))) float f32x4;

#define AS_G(p) ((__attribute__((address_space(1))) void*)(p))
#define AS_L(p) ((__attribute__((address_space(3))) void*)(p))

__device__ __forceinline__ unsigned short f2bf(float f) {
  unsigned int u = __float_as_uint(f);
  unsigned int lsb = (u >> 16) & 1u;
  u += 0x7fffu + lsb;
  return (unsigned short)(u >> 16);
}

#define WAITV(n) asm volatile("s_waitcnt vmcnt(" #n ")" ::: "memory")
#define BARRIER() do { asm volatile("" ::: "memory");                         \
    __builtin_amdgcn_s_barrier();                                             \
    asm volatile("" ::: "memory");                                            \
    __builtin_amdgcn_sched_barrier(0); } while (0)

// ---------- 256xBN 2-region NT GEMM, counted vmcnt ----------
// Template MI selects geometry (R0-R4 post-mortem: schedule variants all hit
// MfmaUtil ~28%; the dominant measured waste is GRID QUANTIZATION -- proj ran
// 1.5 rounds as 2, PV ran 0.5 rounds with half the chip idle):
//   MI=8: BM=BN=256, 8 waves 2M x 4N, per-wave 128x64, acc[8][4], LDS 128K.
//         (QK control path -- identical to R4.)
//   MI=4: BM=256, BN=128, 8 waves 4M x 2N, per-wave 64x64, acc[4][4],
//         LDS 96K. proj grid 24x32=768=3.0 rounds, PV 8x8x4=256=1.0 round.
// Swizzle (measured 0 SQ_LDS_BANK_CONFLICT): LDS row = 8 chunks of 8 elems
// (16B); slot s of row r holds k-chunk s ^ (r&7); staging pre-swizzles the
// GLOBAL source so the LDS dest stays linear (global_load_lds requirement).
//
// Two regions per K-tile, ds_reads issued at region top service under the
// MFMA cluster; counted vmcnt never reaches 0 in steady state (m218).
// MI=8 staging (8 loads/tile): carry A q1,q3 in R1 (other buf), lead
//   A q0,q2 + B q0-3 in R2 (this buf); tile-end vmcnt(6); prologue vmcnt(8).
// MI=4 staging (6 loads/tile): all A reads issue in R1, B jh0 reads in R1,
//   B jh1 reads in R2. carry B q0,q1 in R1 (other buf, barrier-ordered after
//   previous tile's reads), lead A q0..q3 in R2 (this buf, barrier-ordered
//   after R1's A read-issues); tile-end vmcnt(4); prologue vmcnt(6).
// WAR/RAW audit per region: every staged block's readers passed a barrier
// before the stage issues; buffer completeness guaranteed by the previous
// tile's counted wait (loads complete oldest-first, m135).
//
// EPI=1: QK epilogue: P' = bf16(exp(acc*scale)) (unnormalized softmax
//        numerator; |acc*scale| small by construction) + fp32 atomic
//        row-sum into rsum.
// EPI=2: QKV projection split: col seg 0 -> qb (+bq), seg 1 -> kb (+bk),
//        seg 2 -> vt TRANSPOSED (+bv) as ushort4.
// EPI=3: PV epilogue: out fp32 = acc / rsum[row].

// stage one 64-row block (1 global_load_lds per thread, 512thr x 16B = 8KB)
#define S64A(ktk, rb, bofs)                                                   \
  __builtin_amdgcn_global_load_lds(                                           \
      AS_G(A + (size_t)(rowBase + (rb) * 64 + r0) * lda + (ktk) + goff),      \
      AS_L(lds + (bofs) + (rb) * 4096 + t * 8), 16, 0, 0)

#define S64B(ktk, rb, bofs)                                                   \
  __builtin_amdgcn_global_load_lds(                                           \
      AS_G(B + (size_t)(colBase + (rb) * 64 + r0) * ldb + (ktk) + goff),      \
      AS_L(lds + (bofs) + 16384 + (rb) * 4096 + t * 8), 16, 0, 0)

// A-frag loads: MI=8 reads half ih (4 frags), MI=4 reads all 4 frags.
#define LOADA8(ih, bofs) do { _Pragma("unroll")                               \
    for (int ks_ = 0; ks_ < 2; ks_++) { _Pragma("unroll")                     \
      for (int ii = 0; ii < 4; ii++) {                                        \
        int row_ = wrow + ((ih) * 4 + ii) * 16 + r16;                         \
        int slot_ = (ks_ * 4 + q) ^ (r16 & 7);                                \
        af[ks_][ii] = *(const bf16x8*)(lds + (bofs) + row_ * 64 + slot_ * 8); \
      } } } while (0)

#define LOADA4(bofs) do { _Pragma("unroll")                                   \
    for (int ks_ = 0; ks_ < 2; ks_++) { _Pragma("unroll")                     \
      for (int ii = 0; ii < 4; ii++) {                                        \
        int row_ = wrow + ii * 16 + r16;                                      \
        int slot_ = (ks_ * 4 + q) ^ (r16 & 7);                                \
        af[ks_][ii] = *(const bf16x8*)(lds + (bofs) + row_ * 64 + slot_ * 8); \
      } } } while (0)

#define LOADB(jh, bofs) do { _Pragma("unroll")                                \
    for (int ks_ = 0; ks_ < 2; ks_++) { _Pragma("unroll")                     \
      for (int jj = 0; jj < 2; jj++) {                                        \
        int row_ = wcol + ((jh) * 2 + jj) * 16 + r16;                         \
        int slot_ = (ks_ * 4 + q) ^ (r16 & 7);                                \
        bfr[ks_][(jh) * 2 + jj] =                                             \
            *(const bf16x8*)(lds + (bofs) + 16384 + row_ * 64 + slot_ * 8);   \
      } } } while (0)

// MFMA cluster over acc rows ihb..ihb+3, cols j0..j1 (per-element
// accumulation order identical to R4: ks inner-most constant, ks0 then ks1).
#define MMQ(ihb, j0, j1) do { __builtin_amdgcn_s_setprio(1); _Pragma("unroll")\
    for (int ks_ = 0; ks_ < 2; ks_++) { _Pragma("unroll")                     \
      for (int ii = 0; ii < 4; ii++) { _Pragma("unroll")                      \
        for (int jj = (j0); jj <= (j1); jj++)                                 \
          acc[(ihb) + ii][jj] = __builtin_amdgcn_mfma_f32_16x16x32_bf16(      \
              af[ks_][ii], bfr[ks_][jj], acc[(ihb) + ii][jj], 0, 0, 0);       \
      } }                                                                     \
    __builtin_amdgcn_s_setprio(0); } while (0)

// MI=8 K-tile (R4's TILE, 8 loads: carry 2 in R1, lead 6 in R2, vmcnt(6))
#define TILE8(ktc, bofs, obofs) do {                                          \
    LOADA8(0, bofs); LOADB(0, bofs); LOADB(1, bofs);                          \
    if ((ktc) && (ktc) + 64 < K) {                                            \
      S64A((ktc) + 64, 1, obofs); S64A((ktc) + 64, 3, obofs);                 \
    }                                                                         \
    MMQ(0, 0, 3);                                                             \
    BARRIER();                                                                \
    LOADA8(1, bofs);                                                          \
    if ((ktc) + 128 < K) {                                                    \
      S64A((ktc) + 128, 0, bofs); S64A((ktc) + 128, 2, bofs);                 \
      S64B((ktc) + 128, 0, bofs); S64B((ktc) + 128, 1, bofs);                 \
      S64B((ktc) + 128, 2, bofs); S64B((ktc) + 128, 3, bofs);                 \
    }                                                                         \
    MMQ(4, 0, 3);                                                             \
    if ((ktc) + 128 < K) { WAITV(6); } else { WAITV(0); }                     \
    BARRIER(); } while (0)

// MI=4 K-tile (6 loads: carry B q0,q1 in R1, lead A q0..q3 in R2, vmcnt(4))
#define TILE4(ktc, bofs, obofs) do {                                          \
    LOADA4(bofs); LOADB(0, bofs);                                             \
    if ((ktc) && (ktc) + 64 < K) {                                            \
      S64B((ktc) + 64, 0, obofs); S64B((ktc) + 64, 1, obofs);                 \
    }                                                                         \
    MMQ(0, 0, 1);                                                             \
    BARRIER();                                                                \
    LOADB(1, bofs);                                                           \
    if ((ktc) + 128 < K) {                                                    \
      S64A((ktc) + 128, 0, bofs); S64A((ktc) + 128, 1, bofs);                 \
      S64A((ktc) + 128, 2, bofs); S64A((ktc) + 128, 3, bofs);                 \
    }                                                                         \
    MMQ(0, 2, 3);                                                             \
    if ((ktc) + 128 < K) { WAITV(4); } else { WAITV(0); }                     \
    BARRIER(); } while (0)

template <int EPI, int MI>
__global__ __launch_bounds__(512, 2) void gemm_2r(
    const unsigned short* __restrict__ A, const unsigned short* __restrict__ B,
    float* __restrict__ Cf, long long sA, long long sB, long long sC,
    int K, int lda, int ldb, int ldc,
    unsigned short* __restrict__ u0, unsigned short* __restrict__ u1,
    unsigned short* __restrict__ u2,
    const float* __restrict__ f0, const float* __restrict__ f1,
    const float* __restrict__ f2,
    float* __restrict__ rsum, float scale)
{
  constexpr int BN = MI * 32;                 // 256 or 128
  constexpr int BUFE = 16384 + BN * 64;       // elems per LDS buffer
  __shared__ unsigned short lds[2 * BUFE];    // 128 KiB (MI=8) / 96 KiB (MI=4)

  const int t = threadIdx.x;
  const int rowBase = blockIdx.y * 256;
  const int colBase = blockIdx.x * BN;
  A += (long long)blockIdx.z * sA;
  B += (long long)blockIdx.z * sB;

  const int l = t & 63;
  const int w = t >> 6;  // 0..7
  const int wrow = (MI == 8) ? (w >> 2) * 128 : (w >> 1) * 64;
  const int wcol = (MI == 8) ? (w & 3) * 64 : (w & 1) * 64;
  const int q = l >> 4;
  const int r16 = l & 15;

  // staging geometry: thread t covers row r0 = t>>3 (of a 64-row block),
  // slot t&7, global k-chunk = (t&7)^(r0&7) (pre-swizzled source).
  const int r0 = t >> 3;                        // 0..63
  const int goff = ((t & 7) ^ (r0 & 7)) << 3;

  f32x4 acc[MI][4] = {};
  bf16x8 af[2][4], bfr[2][4];

  // prologue: tile0 -> buf0, tile1 -> buf1; drain tile0 only.
  S64A(0, 0, 0); S64A(0, 1, 0); S64A(0, 2, 0); S64A(0, 3, 0);
  S64B(0, 0, 0); S64B(0, 1, 0);
  if constexpr (MI == 8) { S64B(0, 2, 0); S64B(0, 3, 0); }
  S64A(64, 0, BUFE); S64A(64, 1, BUFE); S64A(64, 2, BUFE); S64A(64, 3, BUFE);
  S64B(64, 0, BUFE); S64B(64, 1, BUFE);
  if constexpr (MI == 8) { S64B(64, 2, BUFE); S64B(64, 3, BUFE); }
  if constexpr (MI == 8) { WAITV(8); } else { WAITV(6); }
  BARRIER();

  for (int kt = 0; kt < K; kt += 128) {   // K is a multiple of 128
    if constexpr (MI == 8) {
      TILE8(kt, 0, BUFE);
      TILE8(kt + 64, BUFE, 0);
    } else {
      TILE4(kt, 0, BUFE);
      TILE4(kt + 64, BUFE, 0);
    }
  }

  // epilogues: C frag layout row=(lane>>4)*4+r, col=lane&15 (m89/m91)
  if (EPI == 1) {
    unsigned short* p16 = u0 + (long long)blockIdx.z * sC;
    float* rs = rsum + (long long)blockIdx.z * 2048;
#pragma unroll
    for (int i = 0; i < MI; i++) {
#pragma unroll
      for (int r = 0; r < 4; r++) {
        int row = rowBase + wrow + i * 16 + q * 4 + r;
        float rowpart = 0.f;
#pragma unroll
        for (int j = 0; j < 4; j++) {
          int col = colBase + wcol + j * 16 + r16;
          float e = __expf(acc[i][j][r] * scale);
          p16[(size_t)row * ldc + col] = f2bf(e);
          rowpart += e;
        }
#pragma unroll
        for (int m = 1; m < 16; m <<= 1) rowpart += __shfl_xor(rowpart, m);
        if (r16 == 0) atomicAdd(rs + row, rowpart);
      }
    }
  } else if (EPI == 2) {
    const int seg = colBase >> 10;  // block-uniform (tile never straddles)
    if (seg < 2) {
      unsigned short* dst = seg ? u1 : u0;
      const float* bias = seg ? f1 : f0;
      const int cb = colBase & 1023;
#pragma unroll
      for (int i = 0; i < MI; i++) {
#pragma unroll
        for (int r = 0; r < 4; r++) {
          int row = rowBase + wrow + i * 16 + q * 4 + r;
#pragma unroll
          for (int j = 0; j < 4; j++) {
            int col = cb + wcol + j * 16 + r16;
            dst[(size_t)row * 1024 + col] = f2bf(acc[i][j][r] + bias[col]);
          }
        }
      }
    } else {
      const int ob = colBase - 2048;
#pragma unroll
      for (int i = 0; i < MI; i++) {
        int posBase = rowBase + wrow + i * 16 + q * 4;
        int b = posBase >> 11;
        int pos = posBase & 2047;
#pragma unroll
        for (int j = 0; j < 4; j++) {
          int o = ob + wcol + j * 16 + r16;
          float bias = f2[o];
          ushort4 pk;
          pk.x = f2bf(acc[i][j][0] + bias);
          pk.y = f2bf(acc[i][j][1] + bias);
          pk.z = f2bf(acc[i][j][2] + bias);
          pk.w = f2bf(acc[i][j][3] + bias);
          *(ushort4*)(u2 + ((size_t)((b << 10) + o) * 2048 + pos)) = pk;
        }
      }
    }
  } else {  // EPI == 3
    float* C = Cf + (long long)blockIdx.z * sC;
    const float* rs = rsum + (long long)blockIdx.z * 2048;
#pragma unroll
    for (int i = 0; i < MI; i++) {
#pragma unroll
      for (int r = 0; r < 4; r++) {
        int row = rowBase + wrow + i * 16 + q * 4 + r;
        float inv = 1.0f / rs[row];
#pragma unroll
        for (int j = 0; j < 4; j++) {
          int col = colBase + wcol + j * 16 + r16;
          C[(size_t)row * ldc + col] = acc[i][j][r] * inv;
        }
      }
    }
  }
}

// ---------- fp32 -> bf16 cast (vectorized) + rsum zero-fill ----------

__global__ __launch_bounds__(256) void cast_f32_to_bf16(
    const float* __restrict__ in, unsigned short* __restrict__ out, int n4,
    float* __restrict__ rzero, int nz4)
{
  int i = blockIdx.x * 256 + threadIdx.x;
  if (i < nz4) ((float4*)rzero)[i] = make_float4(0.f, 0.f, 0.f, 0.f);
  if (i >= n4) return;
  float4 v = ((const float4*)in)[i];
  ushort4 o;
  o.x = f2bf(v.x); o.y = f2bf(v.y); o.z = f2bf(v.z); o.w = f2bf(v.w);
  ((ushort4*)out)[i] = o;
}

// ---------- W transpose: WT[z][h, d] = bf16(W_z[d, h]), 1024x1024, z=0..2 ----------

__global__ __launch_bounds__(256) void wtrans(
    const float* __restrict__ Wq, const float* __restrict__ Wk,
    const float* __restrict__ Wv, unsigned short* __restrict__ WT)
{
  __shared__ float tile[32][33];
  const float* in = blockIdx.z == 0 ? Wq : (blockIdx.z == 1 ? Wk : Wv);
  unsigned short* out = WT + (size_t)blockIdx.z * 1024 * 1024;
  const int bc = blockIdx.x * 32;  // h
  const int br = blockIdx.y * 32;  // d
  const int tx = threadIdx.x;
  const int ty = threadIdx.y;
#pragma unroll
  for (int i = 0; i < 4; i++)
    tile[ty + i * 8][tx] = in[(size_t)(br + ty + i * 8) * 1024 + bc + tx];
  __syncthreads();
#pragma unroll
  for (int i = 0; i < 4; i++)
    out[(size_t)(bc + ty + i * 8) * 1024 + br + tx] = f2bf(tile[tx][ty + i * 8]);
}

// ---------- driver ----------

extern "C" void kernel_launch(void* const* d_in, const int* in_sizes, int n_in,
                              void* d_out, int out_size, void* d_ws, size_t ws_size,
                              hipStream_t stream) {
  (void)in_sizes; (void)n_in; (void)out_size;

  const float* x  = (const float*)d_in[0];
  const float* Wq = (const float*)d_in[1];
  const float* bq = (const float*)d_in[2];
  const float* Wk = (const float*)d_in[3];
  const float* bk = (const float*)d_in[4];
  const float* Wv = (const float*)d_in[5];
  const float* bv = (const float*)d_in[6];
  float* out = (float*)d_out;

  const int Nb = 4, L = 2048, D = 1024, H = 1024, O = 1024;
  const int M = Nb * L;      // 8192
  const int NQKV = 3 * H;    // 3072

  char* ws = (char*)d_ws;
  size_t off = 0;
  unsigned short* xb = (unsigned short*)(ws + off); off += (size_t)M * D * 2;
  unsigned short* qb = (unsigned short*)(ws + off); off += (size_t)M * H * 2;
  unsigned short* kb = (unsigned short*)(ws + off); off += (size_t)M * H * 2;
  unsigned short* vt = (unsigned short*)(ws + off); off += (size_t)M * O * 2;
  unsigned short* WT = (unsigned short*)(ws + off); off += (size_t)NQKV * D * 2;
  unsigned short* P  = (unsigned short*)(ws + off); off += (size_t)Nb * L * L * 2;
  float* rsum = (float*)(ws + off); off += (size_t)Nb * L * 4;
  if (ws_size < off) return;

  dim3 blk256(256);
  dim3 blk512(512);

  // x -> bf16, and zero the row-sum accumulator (ws is poisoned every call)
  cast_f32_to_bf16<<<(M * D / 4 + 255) / 256, blk256, 0, stream>>>(
      x, xb, M * D / 4, rsum, Nb * L / 4);

  // WT = concat(Wq^T, Wk^T, Wv^T) as bf16 [3072, 1024] (one launch, z=3)
  wtrans<<<dim3(32, 32, 3), dim3(32, 8), 0, stream>>>(Wq, Wk, Wv, WT);

  // fused projections: q -> qb, k -> kb, v -> vt (transposed), + biases
  // MI=4 tile 256x128: grid 24x32 = 768 blocks = 3.0 EXACT rounds
  gemm_2r<2, 4><<<dim3(NQKV / 128, M / 256, 1), blk512, 0, stream>>>(
      xb, WT, nullptr, 0, 0, 0, D, D, D, 0,
      qb, kb, vt, bq, bk, bv, nullptr, 0.f);

  // QK + exp + row-sum atomics: P'[b] = exp(q k^T * scale)
  // MI=8 tile 256x256 (R4 control path): grid 8x8x4 = 256 = 1.0 round
  gemm_2r<1, 8><<<dim3(L / 256, L / 256, Nb), blk512, 0, stream>>>(
      qb, kb, nullptr, (long long)L * H, (long long)L * H, (long long)L * L,
      H, H, H, L,
      P, nullptr, nullptr, nullptr, nullptr, nullptr,
      rsum, 0.022097086912079608f /* 1/sqrt(2048) */);

  // out[b] = (P'[b] @ vt[b]^T) / rsum
  // MI=4 tile 256x128: grid 8x8x4 = 256 blocks = 1.0 EXACT round (was 0.5)
  gemm_2r<3, 4><<<dim3(O / 128, L / 256, Nb), blk512, 0, stream>>>(
      P, vt, out, (long long)L * L, (long long)O * L, (long long)L * O,
      L, L, L, O,
      nullptr, nullptr, nullptr, nullptr, nullptr, nullptr,
      rsum, 0.f);
}